// Round 7
// baseline (110.913 us; speedup 1.0000x reference)
//
#include <hip/hip_runtime.h>

#define QK_SCALE 0.17677669529663689f  // 1/sqrt(32)

typedef float f4 __attribute__((ext_vector_type(4)));
typedef short bf16x8 __attribute__((ext_vector_type(8)));
typedef float f32x4 __attribute__((ext_vector_type(4)));
typedef unsigned short us4 __attribute__((ext_vector_type(4)));
typedef unsigned int u32x2 __attribute__((ext_vector_type(2)));

__device__ __forceinline__ unsigned short f2bf(float x){
  unsigned int u = __float_as_uint(x);
  u += 0x7fffu + ((u >> 16) & 1u);
  return (unsigned short)(u >> 16);
}
__device__ __forceinline__ float bf2f(unsigned short h){
  return __uint_as_float(((unsigned int)h) << 16);
}
__device__ __forceinline__ unsigned int cvtpk(float lo, float hi){
  unsigned int r;
  asm volatile("v_cvt_pk_bf16_f32 %0, %1, %2" : "=v"(r) : "v"(lo), "v"(hi));
  return r;
}
__device__ __forceinline__ f32x4 mfma16(bf16x8 a, bf16x8 b, f32x4 c){
  return __builtin_amdgcn_mfma_f32_16x16x32_bf16(a, b, c, 0, 0, 0);
}
__device__ __forceinline__ void gload_lds16(const void* g, void* s){
  __builtin_amdgcn_global_load_lds(
      (const __attribute__((address_space(1))) unsigned int*)g,
      (__attribute__((address_space(3))) unsigned int*)s, 16, 0, 0);
}

// ---------------- Kernel 0: pack weights into MFMA B-fragment order ----------------
// layout per matrix (K=128, N=128): [nt(8)][kt(4)][hl(2)][lane(64)][e(8)] bf16
// value = W[kt*32 + (lane>>4)*8 + e][nt*16 + (lane&15)]  (wq pre-scaled)
__global__ __launch_bounds__(256)
void k_prep(const float* __restrict__ wq, const float* __restrict__ wk,
            const float* __restrict__ wv, const float* __restrict__ wg,
            const float* __restrict__ wo, unsigned short* __restrict__ pk)
{
  const int m = blockIdx.x;
  const float* W = (m==0)? wq : (m==1)? wk : (m==2)? wv : (m==3)? wg : wo;
  const float scale = (m==0)? QK_SCALE : 1.0f;
  unsigned short* dst = pk + (long)m * 32768;
  for (int ent = threadIdx.x; ent < 2048; ent += 256){
    const int l = ent & 63, ktn = ent >> 6;
    const int kt = ktn & 3, nt = ktn >> 2;
    unsigned short* ph = dst + ((nt*4 + kt)*2 + 0)*512 + l*8;
    unsigned short* pl = dst + ((nt*4 + kt)*2 + 1)*512 + l*8;
    #pragma unroll
    for (int e = 0; e < 8; ++e){
      const int row = kt*32 + (l>>4)*8 + e;
      const int col = nt*16 + (l&15);
      float v = W[row*128 + col] * scale;
      unsigned short hh = f2bf(v);
      ph[e] = hh;
      pl[e] = f2bf(v - bf2f(hh));
    }
  }
}

// ---------------- Kernel 1: LN + q/k/v/g projections + pair bias ----------------
// Direct global->reg loads in frag positions, LN via shuffles; one barrier.
__global__ __launch_bounds__(512, 4)
void k_proj(const float* __restrict__ act, const float* __restrict__ ln_g,
            const float* __restrict__ ln_b, const float* __restrict__ w2d,
            const unsigned short* __restrict__ pk, const float* __restrict__ bg,
            unsigned short* __restrict__ qf, unsigned short* __restrict__ kf,
            unsigned short* __restrict__ vt, unsigned short* __restrict__ gg,
            float* __restrict__ b2d)
{
  __shared__ unsigned short afr[8*4*2*512];  // 64 KB A-fragments hi/lo
  __shared__ unsigned short sc[4*640];       // 5 KB per-wave C->frag bounce (waves 0-3)
  const int t = threadIdx.x, w = t>>6, l = t&63, g16 = l>>4, c = l&15;
  const long p0 = (long)blockIdx.x * 128;
  const int bi = (int)(p0 >> 8);
  const int qb0 = (int)(p0 & 255);
  const int row = w*16 + c;

  // ---- load the lane's 32 act values (frag positions), LN, build afr + pair bias
  {
    const float* ap = act + (p0 + row)*128;
    f4 xv[4][2];
    #pragma unroll
    for (int kt = 0; kt < 4; ++kt){
      xv[kt][0] = *(const f4*)(ap + kt*32 + g16*8);
      xv[kt][1] = *(const f4*)(ap + kt*32 + g16*8 + 4);
    }
    float s = 0.f, s2 = 0.f;
    #pragma unroll
    for (int kt = 0; kt < 4; ++kt)
      #pragma unroll
      for (int u = 0; u < 2; ++u)
        #pragma unroll
        for (int e = 0; e < 4; ++e){
          float x = xv[kt][u][e]; s += x; s2 += x*x;
        }
    s += __shfl_xor(s,16); s2 += __shfl_xor(s2,16);
    s += __shfl_xor(s,32); s2 += __shfl_xor(s2,32);
    const float mu = s*(1.f/128.f);
    const float iv = rsqrtf(fmaxf(s2*(1.f/128.f)-mu*mu,0.f)+1e-5f);

    float pb0=0.f, pb1=0.f, pb2=0.f, pb3=0.f;
    #pragma unroll
    for (int kt = 0; kt < 4; ++kt){
      bf16x8 hv, lv;
      #pragma unroll
      for (int u = 0; u < 2; ++u){
        const int cb = kt*32 + g16*8 + u*4;
        f4 lg = *(const f4*)(ln_g + cb);
        f4 lb = *(const f4*)(ln_b + cb);
        #pragma unroll
        for (int e0 = 0; e0 < 4; ++e0){
          float vv = (xv[kt][u][e0]-mu)*iv*lg[e0] + lb[e0];
          f4 wp = *(const f4*)(w2d + (cb+e0)*4);
          pb0 += vv*wp[0]; pb1 += vv*wp[1]; pb2 += vv*wp[2]; pb3 += vv*wp[3];
          unsigned short hh = f2bf(vv);
          hv[u*4+e0] = (short)hh;
          lv[u*4+e0] = (short)f2bf(vv - bf2f(hh));
        }
      }
      *(bf16x8*)&afr[((w*4+kt)*2+0)*512 + l*8] = hv;
      *(bf16x8*)&afr[((w*4+kt)*2+1)*512 + l*8] = lv;
    }
    pb0 += __shfl_xor(pb0,16); pb1 += __shfl_xor(pb1,16);
    pb2 += __shfl_xor(pb2,16); pb3 += __shfl_xor(pb3,16);
    pb0 += __shfl_xor(pb0,32); pb1 += __shfl_xor(pb1,32);
    pb2 += __shfl_xor(pb2,32); pb3 += __shfl_xor(pb3,32);
    const float pbsel = (g16==0)? pb0 : (g16==1)? pb1 : (g16==2)? pb2 : pb3;
    b2d[g16*65536 + (int)p0 + row] = pbsel;
  }
  __syncthreads();

  // ---- GEMM over 32 N-tiles; wave owns 4 N-tiles (2 passes x 2); zero barriers
  #pragma unroll
  for (int pass = 0; pass < 2; ++pass){
    bf16x8 bh0[4], bl0[4], bh1[4], bl1[4];
    { const int ntg = w*4 + pass*2;
      #pragma unroll
      for (int kt = 0; kt < 4; ++kt){
        bh0[kt] = *(const bf16x8*)(pk + ((ntg*4+kt)*2+0)*512 + l*8);
        bl0[kt] = *(const bf16x8*)(pk + ((ntg*4+kt)*2+1)*512 + l*8);
        bh1[kt] = *(const bf16x8*)(pk + (((ntg+1)*4+kt)*2+0)*512 + l*8);
        bl1[kt] = *(const bf16x8*)(pk + (((ntg+1)*4+kt)*2+1)*512 + l*8);
      } }
    for (int rt = 0; rt < 8; ++rt){
      bf16x8 ah[4], al[4];
      #pragma unroll
      for (int kt = 0; kt < 4; ++kt){
        ah[kt] = *(const bf16x8*)&afr[((rt*4+kt)*2+0)*512 + l*8];
        al[kt] = *(const bf16x8*)&afr[((rt*4+kt)*2+1)*512 + l*8];
      }
      f32x4 a0 = {0.f,0.f,0.f,0.f}, a1 = {0.f,0.f,0.f,0.f};
      #pragma unroll
      for (int kt = 0; kt < 4; ++kt){
        a0 = mfma16(ah[kt], bh0[kt], a0);
        a1 = mfma16(ah[kt], bh1[kt], a1);
        a0 = mfma16(ah[kt], bl0[kt], a0);
        a1 = mfma16(ah[kt], bl1[kt], a1);
        a0 = mfma16(al[kt], bh0[kt], a0);
        a1 = mfma16(al[kt], bh1[kt], a1);
      }
      if (w < 4){           // q/k: C-tile -> row-major frag via wave-local bounce
        unsigned short* scw = sc + w*640;
        #pragma unroll
        for (int j = 0; j < 4; ++j){
          scw[(g16*4+j)*40 + c]      = f2bf(a0[j]);
          scw[(g16*4+j)*40 + 16 + c] = f2bf(a1[j]);
        }
        asm volatile("" ::: "memory");
        bf16x8 fr = *(const bf16x8*)&scw[c*40 + g16*8];
        const int head = (w&1)*2 + pass;
        unsigned short* dst = (w < 2) ? qf : kf;
        *(bf16x8*)&dst[(((long)bi*4+head)*16 + (qb0>>4) + rt)*512 + l*8] = fr;
        asm volatile("" ::: "memory");
      } else if (w < 6){    // v: transposed swizzled image
        const int ntv0 = (w-4)*4 + pass*2;
        const int kv = qb0 + rt*16 + g16*4;
        #pragma unroll
        for (int np = 0; np < 2; ++np){
          const int colg = (ntv0+np)*16 + c;
          const int head = colg >> 5, d = colg & 31;
          f32x4 aa = np ? a1 : a0;
          us4 v4;
          #pragma unroll
          for (int j = 0; j < 4; ++j) v4[j] = f2bf(aa[j]);
          const int vb = (d*512 + kv*2) ^ ((d&7)<<4);
          *(us4*)((char*)vt + ((long)bi*4+head)*16384 + vb) = v4;
        }
      } else {              // g: sigmoid(x@wg + bg), bf16 row-major
        const int colb = (w-6)*64 + pass*32;
        const int row0 = (int)p0 + rt*16 + g16*4;
        const float bg0 = bg[colb + c];
        const float bg1 = bg[colb + 16 + c];
        #pragma unroll
        for (int j = 0; j < 4; ++j){
          float g0 = 1.f/(1.f + __expf(-(a0[j] + bg0)));
          float g1 = 1.f/(1.f + __expf(-(a1[j] + bg1)));
          gg[(row0+j)*128 + colb + c]      = f2bf(g0);
          gg[(row0+j)*128 + colb + 16 + c] = f2bf(g1);
        }
      }
    }
  }
}

// ---------------- Kernel 2: attention (i,h)-block, 8 waves x 32 q-rows ----------
// Swapped-operand: S^T = mfma(K,Q); softmax over regs + 2 shuffles; P packed via
// v_cvt_pk_bf16_f32 into per-wave 2KB swizzled LDS (4-phase PV); O^T = mfma(V^T,P).
__global__ __launch_bounds__(512, 4)
void k_attn(const unsigned short* __restrict__ qf, const unsigned short* __restrict__ kfg,
            const unsigned short* __restrict__ vt, const unsigned short* __restrict__ gg,
            const float* __restrict__ b2d, const float* __restrict__ mask,
            unsigned short* __restrict__ obf)
{
  __shared__ unsigned short k_s[16*512];   // 16 KB K fragments
  __shared__ unsigned short v_s[8192];     // 16 KB V^T swizzled image
  __shared__ unsigned short p_s[8*1024];   // 16 KB per-wave P[16 q][64 k] swizzled
  __shared__ float mb_s[256];
  const int t = threadIdx.x, w = t>>6, l = t&63, g16 = l>>4, c = l&15;
  const int bi = blockIdx.x >> 2, h = blockIdx.x & 3;
  const int base = (bi*4+h)*8192;

  #pragma unroll
  for (int cc = 0; cc < 4; ++cc){
    const int ch = w*4 + cc;
    if (ch < 16) gload_lds16(kfg + base + ch*512 + l*8, k_s + ch*512);
    else         gload_lds16(vt + base + (ch-16)*512 + l*8, v_s + (ch-16)*512);
  }
  if (t < 256) mb_s[t] = 1e9f * (mask[bi*256 + t] - 1.0f);
  asm volatile("s_waitcnt vmcnt(0)" ::: "memory");
  __syncthreads();

  char* pw = (char*)(p_s + w*1024);
  const int swz = (c&7)<<4;

  for (int im = 0; im < 2; ++im){
    const int q0 = w*32 + im*16;
    const bf16x8 qfr = *(const bf16x8*)(qf + base + (q0>>4)*512 + l*8);
    const float* bq = b2d + h*65536 + (q0 + c)*256 + g16*4;
    // ---- S^T = K Q^T + bias (bias rows k consecutive -> f4 loads)
    f32x4 sa[16];
    #pragma unroll
    for (int nt = 0; nt < 16; ++nt){
      f4 bv = *(const f4*)(bq + nt*16);
      f4 mv = *(const f4*)&mb_s[nt*16 + g16*4];
      f32x4 ci;
      ci[0]=bv[0]+mv[0]; ci[1]=bv[1]+mv[1]; ci[2]=bv[2]+mv[2]; ci[3]=bv[3]+mv[3];
      sa[nt] = mfma16(*(const bf16x8*)(k_s + nt*512 + l*8), qfr, ci);
    }
    // ---- softmax over k: 64 per-lane values + cross-g16 (2 shuffles)
    float mx = fmaxf(fmaxf(sa[0][0], sa[0][1]), fmaxf(sa[0][2], sa[0][3]));
    #pragma unroll
    for (int nt = 1; nt < 16; ++nt)
      mx = fmaxf(mx, fmaxf(fmaxf(sa[nt][0], sa[nt][1]), fmaxf(sa[nt][2], sa[nt][3])));
    mx = fmaxf(mx, __shfl_xor(mx, 16));
    mx = fmaxf(mx, __shfl_xor(mx, 32));
    const float nmx = -mx * 1.44269504f;
    float sum = 0.f;
    #pragma unroll
    for (int nt = 0; nt < 16; ++nt){
      #pragma unroll
      for (int j = 0; j < 4; ++j){
        float e = exp2f(fmaf(sa[nt][j], 1.44269504f, nmx));
        sa[nt][j] = e; sum += e;
      }
    }
    sum += __shfl_xor(sum, 16);
    sum += __shfl_xor(sum, 32);
    const float inv = 1.f / sum;
    // ---- PV in four 64-k phases: pack P (cvt_pk + b64 write), read b128, MFMA
    f32x4 oa0 = {0.f,0.f,0.f,0.f}, oa1 = {0.f,0.f,0.f,0.f};
    #pragma unroll
    for (int p4 = 0; p4 < 4; ++p4){
      #pragma unroll
      for (int ntl = 0; ntl < 4; ++ntl){
        const int nt = p4*4 + ntl;
        u32x2 pk2;
        pk2[0] = cvtpk(sa[nt][0], sa[nt][1]);
        pk2[1] = cvtpk(sa[nt][2], sa[nt][3]);
        *(u32x2*)(pw + c*128 + ((ntl*32 + g16*8) ^ swz)) = pk2;
      }
      asm volatile("s_waitcnt lgkmcnt(0)" ::: "memory");
      __builtin_amdgcn_sched_barrier(0);
      #pragma unroll
      for (int ktl = 0; ktl < 2; ++ktl){
        const int kt = p4*2 + ktl;
        bf16x8 pf = *(const bf16x8*)(pw + c*128 + ((ktl*64 + g16*16) ^ swz));
        const int vb0 = ((c*512      + kt*64 + g16*16) ^ swz);
        const int vb1 = (((16+c)*512 + kt*64 + g16*16) ^ swz);
        oa0 = mfma16(*(const bf16x8*)((const char*)v_s + vb0), pf, oa0);
        oa1 = mfma16(*(const bf16x8*)((const char*)v_s + vb1), pf, oa1);
      }
      asm volatile("" ::: "memory");
      __builtin_amdgcn_sched_barrier(0);
    }
    // ---- epilogue: O[q=q0+c][d], gate, cvt_pk, store 8B
    const int row = bi*256 + q0 + c;
    us4 gv0 = *(const us4*)&gg[row*128 + h*32 + g16*4];
    us4 gv1 = *(const us4*)&gg[row*128 + h*32 + 16 + g16*4];
    u32x2 o0, o1;
    o0[0] = cvtpk(oa0[0]*inv*bf2f(gv0[0]), oa0[1]*inv*bf2f(gv0[1]));
    o0[1] = cvtpk(oa0[2]*inv*bf2f(gv0[2]), oa0[3]*inv*bf2f(gv0[3]));
    o1[0] = cvtpk(oa1[0]*inv*bf2f(gv1[0]), oa1[1]*inv*bf2f(gv1[1]));
    o1[1] = cvtpk(oa1[2]*inv*bf2f(gv1[2]), oa1[3]*inv*bf2f(gv1[3]));
    *(u32x2*)&obf[row*128 + h*32 + g16*4]      = o0;
    *(u32x2*)&obf[row*128 + h*32 + 16 + g16*4] = o1;
  }
}

// ---------------- Kernel 3: out = o_gated(bf16) @ wo + bo ----------------
// A-frags = row-major 16B segments staged via global_load_lds; split-B in regs.
__global__ __launch_bounds__(512, 4)
void k_out(const unsigned short* __restrict__ obf, const unsigned short* __restrict__ pko,
           const float* __restrict__ bo, float* __restrict__ out)
{
  __shared__ unsigned short afr[32*512];   // 32 KB
  const int t = threadIdx.x, w = t>>6, l = t&63, g16 = l>>4, c = l&15;
  const long p0 = (long)blockIdx.x * 128;

  #pragma unroll
  for (int u = 0; u < 4; ++u){
    const int pr = w*4 + u;            // (rt,kt) pair 0..31
    const int rt = pr >> 2, kt = pr & 3;
    gload_lds16(obf + (p0 + rt*16 + c)*128 + kt*32 + g16*8, afr + pr*512);
  }
  asm volatile("s_waitcnt vmcnt(0)" ::: "memory");
  __syncthreads();

  bf16x8 bh[4], bl[4];
  #pragma unroll
  for (int kt = 0; kt < 4; ++kt){
    bh[kt] = *(const bf16x8*)(pko + ((w*4+kt)*2+0)*512 + l*8);
    bl[kt] = *(const bf16x8*)(pko + ((w*4+kt)*2+1)*512 + l*8);
  }
  const float bov = bo[w*16 + c];
  for (int rt = 0; rt < 8; ++rt){
    f32x4 a0 = {bov, bov, bov, bov};
    #pragma unroll
    for (int kt = 0; kt < 4; ++kt){
      bf16x8 af = *(const bf16x8*)&afr[(rt*4+kt)*512 + l*8];
      a0 = mfma16(af, bh[kt], a0);
      a0 = mfma16(af, bl[kt], a0);
    }
    const int row0 = (int)p0 + rt*16 + g16*4;
    #pragma unroll
    for (int j = 0; j < 4; ++j)
      out[(row0+j)*128 + w*16 + c] = a0[j];
  }
}

extern "C" void kernel_launch(void* const* d_in, const int* in_sizes, int n_in,
                              void* d_out, int out_size, void* d_ws, size_t ws_size,
                              hipStream_t stream) {
  const float* act  = (const float*)d_in[0];
  const float* mask = (const float*)d_in[1];
  const float* ln_g = (const float*)d_in[2];
  const float* ln_b = (const float*)d_in[3];
  const float* w2d  = (const float*)d_in[4];
  const float* wq   = (const float*)d_in[5];
  const float* wk   = (const float*)d_in[6];
  const float* wv   = (const float*)d_in[7];
  const float* wg   = (const float*)d_in[8];
  const float* bg   = (const float*)d_in[9];
  const float* wo   = (const float*)d_in[10];
  const float* bo   = (const float*)d_in[11];
  float* out = (float*)d_out;

  char* ws = (char*)d_ws;
  unsigned short* qf  = (unsigned short*)(ws);                 // 16.7 MB frag q
  unsigned short* kfb = (unsigned short*)(ws + 16777216L);     // 16.7 MB frag k
  unsigned short* vt  = (unsigned short*)(ws + 33554432L);     // 16.7 MB swizzled V^T
  unsigned short* gg  = (unsigned short*)(ws + 50331648L);     // 16.7 MB gate bf16
  unsigned short* obf = (unsigned short*)(ws + 67108864L);     // 16.7 MB gated o bf16
  float* b2d = (float*)(ws + 83886080L);                       // 1 MB pair bias
  unsigned short* pk = (unsigned short*)(ws + 84934656L);      // 320 KB packed weights

  k_prep<<<5, 256, 0, stream>>>(wq, wk, wv, wg, wo, pk);
  k_proj<<<512, 512, 0, stream>>>(act, ln_g, ln_b, w2d, pk, bg,
                                  qf, kfb, vt, gg, b2d);
  k_attn<<<1024, 512, 0, stream>>>(qf, kfb, vt, gg, b2d, mask, obf);
  k_out<<<512, 512, 0, stream>>>(obf, pk + 4*32768, bo, out);
}

// Round 8
// 109.729 us; speedup vs baseline: 1.0108x; 1.0108x over previous
//
#include <hip/hip_runtime.h>

#define QK_SCALE 0.17677669529663689f  // 1/sqrt(32)

typedef float f4 __attribute__((ext_vector_type(4)));
typedef short bf16x8 __attribute__((ext_vector_type(8)));
typedef float f32x4 __attribute__((ext_vector_type(4)));
typedef unsigned short us4 __attribute__((ext_vector_type(4)));
typedef unsigned int u32x2 __attribute__((ext_vector_type(2)));
typedef unsigned int u32x4 __attribute__((ext_vector_type(4)));

__device__ __forceinline__ unsigned short f2bf(float x){
  unsigned int u = __float_as_uint(x);
  u += 0x7fffu + ((u >> 16) & 1u);
  return (unsigned short)(u >> 16);
}
__device__ __forceinline__ float bf2f(unsigned short h){
  return __uint_as_float(((unsigned int)h) << 16);
}
__device__ __forceinline__ unsigned int cvtpk(float lo, float hi){
  unsigned int r;
  asm volatile("v_cvt_pk_bf16_f32 %0, %1, %2" : "=v"(r) : "v"(lo), "v"(hi));
  return r;
}
__device__ __forceinline__ f32x4 mfma16(bf16x8 a, bf16x8 b, f32x4 c){
  return __builtin_amdgcn_mfma_f32_16x16x32_bf16(a, b, c, 0, 0, 0);
}
__device__ __forceinline__ void gload_lds16(const void* g, void* s){
  __builtin_amdgcn_global_load_lds(
      (const __attribute__((address_space(1))) unsigned int*)g,
      (__attribute__((address_space(3))) unsigned int*)s, 16, 0, 0);
}

// ---------------- Kernel 0: pack weights into MFMA B-fragment order ----------------
// layout per matrix (K=128, N=128): [nt(8)][kt(4)][hl(2)][lane(64)][e(8)] bf16
// value = W[kt*32 + (lane>>4)*8 + e][nt*16 + (lane&15)]  (wq pre-scaled)
__global__ __launch_bounds__(256)
void k_prep(const float* __restrict__ wq, const float* __restrict__ wk,
            const float* __restrict__ wv, const float* __restrict__ wg,
            const float* __restrict__ wo, unsigned short* __restrict__ pk)
{
  const int m = blockIdx.x;
  const float* W = (m==0)? wq : (m==1)? wk : (m==2)? wv : (m==3)? wg : wo;
  const float scale = (m==0)? QK_SCALE : 1.0f;
  unsigned short* dst = pk + (long)m * 32768;
  for (int ent = threadIdx.x; ent < 2048; ent += 256){
    const int l = ent & 63, ktn = ent >> 6;
    const int kt = ktn & 3, nt = ktn >> 2;
    unsigned short* ph = dst + ((nt*4 + kt)*2 + 0)*512 + l*8;
    unsigned short* pl = dst + ((nt*4 + kt)*2 + 1)*512 + l*8;
    #pragma unroll
    for (int e = 0; e < 8; ++e){
      const int row = kt*32 + (l>>4)*8 + e;
      const int col = nt*16 + (l&15);
      float v = W[row*128 + col] * scale;
      unsigned short hh = f2bf(v);
      ph[e] = hh;
      pl[e] = f2bf(v - bf2f(hh));
    }
  }
}

// ---------------- Kernel 1: LN + q/k/v/g projections + pair bias ----------------
// Direct global->reg loads in frag positions, LN via shuffles; one barrier.
__global__ __launch_bounds__(512, 4)
void k_proj(const float* __restrict__ act, const float* __restrict__ ln_g,
            const float* __restrict__ ln_b, const float* __restrict__ w2d,
            const unsigned short* __restrict__ pk, const float* __restrict__ bg,
            unsigned short* __restrict__ qf, unsigned short* __restrict__ kf,
            unsigned short* __restrict__ vt, unsigned short* __restrict__ gg,
            unsigned short* __restrict__ b2dh)
{
  __shared__ unsigned short afr[8*4*2*512];  // 64 KB A-fragments hi/lo
  __shared__ unsigned short sc[4*640];       // 5 KB per-wave C->frag bounce (waves 0-3)
  const int t = threadIdx.x, w = t>>6, l = t&63, g16 = l>>4, c = l&15;
  const long p0 = (long)blockIdx.x * 128;
  const int bi = (int)(p0 >> 8);
  const int qb0 = (int)(p0 & 255);
  const int row = w*16 + c;

  // ---- load the lane's 32 act values (frag positions), LN, build afr + pair bias
  {
    const float* ap = act + (p0 + row)*128;
    f4 xv[4][2];
    #pragma unroll
    for (int kt = 0; kt < 4; ++kt){
      xv[kt][0] = *(const f4*)(ap + kt*32 + g16*8);
      xv[kt][1] = *(const f4*)(ap + kt*32 + g16*8 + 4);
    }
    float s = 0.f, s2 = 0.f;
    #pragma unroll
    for (int kt = 0; kt < 4; ++kt)
      #pragma unroll
      for (int u = 0; u < 2; ++u)
        #pragma unroll
        for (int e = 0; e < 4; ++e){
          float x = xv[kt][u][e]; s += x; s2 += x*x;
        }
    s += __shfl_xor(s,16); s2 += __shfl_xor(s2,16);
    s += __shfl_xor(s,32); s2 += __shfl_xor(s2,32);
    const float mu = s*(1.f/128.f);
    const float iv = rsqrtf(fmaxf(s2*(1.f/128.f)-mu*mu,0.f)+1e-5f);

    float pb0=0.f, pb1=0.f, pb2=0.f, pb3=0.f;
    #pragma unroll
    for (int kt = 0; kt < 4; ++kt){
      bf16x8 hv, lv;
      #pragma unroll
      for (int u = 0; u < 2; ++u){
        const int cb = kt*32 + g16*8 + u*4;
        f4 lg = *(const f4*)(ln_g + cb);
        f4 lb = *(const f4*)(ln_b + cb);
        #pragma unroll
        for (int e0 = 0; e0 < 4; ++e0){
          float vv = (xv[kt][u][e0]-mu)*iv*lg[e0] + lb[e0];
          f4 wp = *(const f4*)(w2d + (cb+e0)*4);
          pb0 += vv*wp[0]; pb1 += vv*wp[1]; pb2 += vv*wp[2]; pb3 += vv*wp[3];
          unsigned short hh = f2bf(vv);
          hv[u*4+e0] = (short)hh;
          lv[u*4+e0] = (short)f2bf(vv - bf2f(hh));
        }
      }
      *(bf16x8*)&afr[((w*4+kt)*2+0)*512 + l*8] = hv;
      *(bf16x8*)&afr[((w*4+kt)*2+1)*512 + l*8] = lv;
    }
    pb0 += __shfl_xor(pb0,16); pb1 += __shfl_xor(pb1,16);
    pb2 += __shfl_xor(pb2,16); pb3 += __shfl_xor(pb3,16);
    pb0 += __shfl_xor(pb0,32); pb1 += __shfl_xor(pb1,32);
    pb2 += __shfl_xor(pb2,32); pb3 += __shfl_xor(pb3,32);
    const float pbsel = (g16==0)? pb0 : (g16==1)? pb1 : (g16==2)? pb2 : pb3;
    b2dh[g16*65536 + (int)p0 + row] = f2bf(pbsel);
  }
  __syncthreads();

  // ---- GEMM over 32 N-tiles; wave owns 4 N-tiles (2 passes x 2); zero barriers
  #pragma unroll
  for (int pass = 0; pass < 2; ++pass){
    bf16x8 bh0[4], bl0[4], bh1[4], bl1[4];
    { const int ntg = w*4 + pass*2;
      #pragma unroll
      for (int kt = 0; kt < 4; ++kt){
        bh0[kt] = *(const bf16x8*)(pk + ((ntg*4+kt)*2+0)*512 + l*8);
        bl0[kt] = *(const bf16x8*)(pk + ((ntg*4+kt)*2+1)*512 + l*8);
        bh1[kt] = *(const bf16x8*)(pk + (((ntg+1)*4+kt)*2+0)*512 + l*8);
        bl1[kt] = *(const bf16x8*)(pk + (((ntg+1)*4+kt)*2+1)*512 + l*8);
      } }
    for (int rt = 0; rt < 8; ++rt){
      bf16x8 ah[4], al[4];
      #pragma unroll
      for (int kt = 0; kt < 4; ++kt){
        ah[kt] = *(const bf16x8*)&afr[((rt*4+kt)*2+0)*512 + l*8];
        al[kt] = *(const bf16x8*)&afr[((rt*4+kt)*2+1)*512 + l*8];
      }
      f32x4 a0 = {0.f,0.f,0.f,0.f}, a1 = {0.f,0.f,0.f,0.f};
      #pragma unroll
      for (int kt = 0; kt < 4; ++kt){
        a0 = mfma16(ah[kt], bh0[kt], a0);
        a1 = mfma16(ah[kt], bh1[kt], a1);
        a0 = mfma16(ah[kt], bl0[kt], a0);
        a1 = mfma16(ah[kt], bl1[kt], a1);
        a0 = mfma16(al[kt], bh0[kt], a0);
        a1 = mfma16(al[kt], bh1[kt], a1);
      }
      if (w < 4){           // q/k: C-tile -> row-major frag via wave-local bounce
        unsigned short* scw = sc + w*640;
        #pragma unroll
        for (int j = 0; j < 4; ++j){
          scw[(g16*4+j)*40 + c]      = f2bf(a0[j]);
          scw[(g16*4+j)*40 + 16 + c] = f2bf(a1[j]);
        }
        asm volatile("" ::: "memory");
        bf16x8 fr = *(const bf16x8*)&scw[c*40 + g16*8];
        const int head = (w&1)*2 + pass;
        unsigned short* dst = (w < 2) ? qf : kf;
        *(bf16x8*)&dst[(((long)bi*4+head)*16 + (qb0>>4) + rt)*512 + l*8] = fr;
        asm volatile("" ::: "memory");
      } else if (w < 6){    // v: transposed swizzled image
        const int ntv0 = (w-4)*4 + pass*2;
        const int kv = qb0 + rt*16 + g16*4;
        #pragma unroll
        for (int np = 0; np < 2; ++np){
          const int colg = (ntv0+np)*16 + c;
          const int head = colg >> 5, d = colg & 31;
          f32x4 aa = np ? a1 : a0;
          us4 v4;
          #pragma unroll
          for (int j = 0; j < 4; ++j) v4[j] = f2bf(aa[j]);
          const int vb = (d*512 + kv*2) ^ ((d&7)<<4);
          *(us4*)((char*)vt + ((long)bi*4+head)*16384 + vb) = v4;
        }
      } else {              // g: sigmoid(x@wg + bg), bf16 row-major
        const int colb = (w-6)*64 + pass*32;
        const int row0 = (int)p0 + rt*16 + g16*4;
        const float bg0 = bg[colb + c];
        const float bg1 = bg[colb + 16 + c];
        #pragma unroll
        for (int j = 0; j < 4; ++j){
          float g0 = 1.f/(1.f + __expf(-(a0[j] + bg0)));
          float g1 = 1.f/(1.f + __expf(-(a1[j] + bg1)));
          gg[(row0+j)*128 + colb + c]      = f2bf(g0);
          gg[(row0+j)*128 + colb + 16 + c] = f2bf(g1);
        }
      }
    }
  }
}

// ---------------- Kernel 2: attention (i,h)-block, 8 waves x 32 q-rows ----------
// S^T = mfma(K,Q) with (mask+bias) C-init; softmax in regs (4 chains + 2 shfl);
// P-frags built in-register via cvt_pk + ds_bpermute (no P LDS, no waitcnt pins);
// O^T = mfma(V^T, P). LDS = 33KB.
__global__ __launch_bounds__(512, 4)
void k_attn(const unsigned short* __restrict__ qf, const unsigned short* __restrict__ kfg,
            const unsigned short* __restrict__ vt, const unsigned short* __restrict__ gg,
            const unsigned short* __restrict__ b2dh, const float* __restrict__ mask,
            unsigned short* __restrict__ obf)
{
  __shared__ unsigned short k_s[16*512];   // 16 KB K fragments
  __shared__ unsigned short v_s[8192];     // 16 KB V^T swizzled image
  __shared__ float mb_s[256];
  const int t = threadIdx.x, w = t>>6, l = t&63, g16 = l>>4, c = l&15;
  const int bi = blockIdx.x >> 2, h = blockIdx.x & 3;
  const int base = (bi*4+h)*8192;

  #pragma unroll
  for (int cc = 0; cc < 4; ++cc){
    const int ch = w*4 + cc;
    if (ch < 16) gload_lds16(kfg + base + ch*512 + l*8, k_s + ch*512);
    else         gload_lds16(vt + base + (ch-16)*512 + l*8, v_s + (ch-16)*512);
  }
  if (t < 256) mb_s[t] = 1e9f * (mask[bi*256 + t] - 1.0f);
  // Q fragments for both im tiles, in flight across the drain
  const bf16x8 qfr0 = *(const bf16x8*)(qf + base + (w*2+0)*512 + l*8);
  const bf16x8 qfr1 = *(const bf16x8*)(qf + base + (w*2+1)*512 + l*8);
  asm volatile("s_waitcnt vmcnt(0)" ::: "memory");
  __syncthreads();

  const int swz = (c&7)<<4;
  const int a0 = (((l & 16) << 1) | c) << 2;   // byte addr of lane (g16&1)*2*16 + c
  const int a1 = a0 + 64;                      // +16 lanes
  const bool hi = (l >= 32);

  #pragma unroll
  for (int im = 0; im < 2; ++im){
    const int q0 = w*32 + im*16;
    const bf16x8 qfr = im ? qfr1 : qfr0;
    const unsigned short* bq = b2dh + h*65536 + (q0 + c)*256 + g16*4;
    // ---- S^T = K Q^T + (mask + bias) C-init; bias bf16 8B loads, counted waits
    f32x4 sa[16];
    #pragma unroll
    for (int nt = 0; nt < 16; ++nt){
      const us4 bh4 = *(const us4*)(bq + nt*16);
      const f4 mv = *(const f4*)&mb_s[nt*16 + g16*4];
      f32x4 ci;
      ci[0] = mv[0] + bf2f(bh4[0]);
      ci[1] = mv[1] + bf2f(bh4[1]);
      ci[2] = mv[2] + bf2f(bh4[2]);
      ci[3] = mv[3] + bf2f(bh4[3]);
      sa[nt] = mfma16(*(const bf16x8*)(k_s + nt*512 + l*8), qfr, ci);
    }
    // ---- max: 4 parallel chains + 2 shfl
    f32x4 mx4 = sa[0];
    #pragma unroll
    for (int nt = 1; nt < 16; ++nt){
      mx4[0] = fmaxf(mx4[0], sa[nt][0]);
      mx4[1] = fmaxf(mx4[1], sa[nt][1]);
      mx4[2] = fmaxf(mx4[2], sa[nt][2]);
      mx4[3] = fmaxf(mx4[3], sa[nt][3]);
    }
    float mx = fmaxf(fmaxf(mx4[0], mx4[1]), fmaxf(mx4[2], mx4[3]));
    mx = fmaxf(mx, __shfl_xor(mx, 16));
    mx = fmaxf(mx, __shfl_xor(mx, 32));
    const float nmx = -mx * 1.44269504f;
    // ---- exp with 4 accumulators
    f32x4 sv = {0.f,0.f,0.f,0.f};
    #pragma unroll
    for (int nt = 0; nt < 16; ++nt){
      #pragma unroll
      for (int j = 0; j < 4; ++j){
        float e = exp2f(fmaf(sa[nt][j], 1.44269504f, nmx));
        sa[nt][j] = e;
        sv[j] += e;
      }
    }
    float sum = (sv[0]+sv[1]) + (sv[2]+sv[3]);
    sum += __shfl_xor(sum, 16);
    sum += __shfl_xor(sum, 32);
    const float inv = 1.f / sum;
    // ---- PV: P-frags via cvt_pk + ds_bpermute, V from LDS; no pins
    f32x4 oa0 = {0.f,0.f,0.f,0.f}, oa1 = {0.f,0.f,0.f,0.f};
    #pragma unroll
    for (int kt = 0; kt < 8; ++kt){
      const unsigned X0 = cvtpk(sa[2*kt][0],   sa[2*kt][1]);
      const unsigned X1 = cvtpk(sa[2*kt][2],   sa[2*kt][3]);
      const unsigned Y0 = cvtpk(sa[2*kt+1][0], sa[2*kt+1][1]);
      const unsigned Y1 = cvtpk(sa[2*kt+1][2], sa[2*kt+1][3]);
      const int pX0 = __builtin_amdgcn_ds_bpermute(a0, (int)X0);
      const int pY0 = __builtin_amdgcn_ds_bpermute(a0, (int)Y0);
      const int pX1 = __builtin_amdgcn_ds_bpermute(a0, (int)X1);
      const int pY1 = __builtin_amdgcn_ds_bpermute(a0, (int)Y1);
      const int pX2 = __builtin_amdgcn_ds_bpermute(a1, (int)X0);
      const int pY2 = __builtin_amdgcn_ds_bpermute(a1, (int)Y0);
      const int pX3 = __builtin_amdgcn_ds_bpermute(a1, (int)X1);
      const int pY3 = __builtin_amdgcn_ds_bpermute(a1, (int)Y1);
      u32x4 pu;
      pu[0] = (unsigned)(hi ? pY0 : pX0);
      pu[1] = (unsigned)(hi ? pY1 : pX1);
      pu[2] = (unsigned)(hi ? pY2 : pX2);
      pu[3] = (unsigned)(hi ? pY3 : pX3);
      const bf16x8 pf = __builtin_bit_cast(bf16x8, pu);
      const int vb0 = ((c*512      + kt*64 + g16*16) ^ swz);
      const int vb1 = (((16+c)*512 + kt*64 + g16*16) ^ swz);
      oa0 = mfma16(*(const bf16x8*)((const char*)v_s + vb0), pf, oa0);
      oa1 = mfma16(*(const bf16x8*)((const char*)v_s + vb1), pf, oa1);
    }
    // ---- epilogue: O[q=q0+c][d], gate, cvt_pk, store 8B
    const int row = bi*256 + q0 + c;
    us4 gv0 = *(const us4*)&gg[row*128 + h*32 + g16*4];
    us4 gv1 = *(const us4*)&gg[row*128 + h*32 + 16 + g16*4];
    u32x2 o0, o1;
    o0[0] = cvtpk(oa0[0]*inv*bf2f(gv0[0]), oa0[1]*inv*bf2f(gv0[1]));
    o0[1] = cvtpk(oa0[2]*inv*bf2f(gv0[2]), oa0[3]*inv*bf2f(gv0[3]));
    o1[0] = cvtpk(oa1[0]*inv*bf2f(gv1[0]), oa1[1]*inv*bf2f(gv1[1]));
    o1[1] = cvtpk(oa1[2]*inv*bf2f(gv1[2]), oa1[3]*inv*bf2f(gv1[3]));
    *(u32x2*)&obf[row*128 + h*32 + g16*4]      = o0;
    *(u32x2*)&obf[row*128 + h*32 + 16 + g16*4] = o1;
  }
}

// ---------------- Kernel 3: out = o_gated(bf16) @ wo + bo ----------------
// A-frags = row-major 16B segments staged via global_load_lds; split-B in regs.
__global__ __launch_bounds__(512, 4)
void k_out(const unsigned short* __restrict__ obf, const unsigned short* __restrict__ pko,
           const float* __restrict__ bo, float* __restrict__ out)
{
  __shared__ unsigned short afr[32*512];   // 32 KB
  const int t = threadIdx.x, w = t>>6, l = t&63, g16 = l>>4, c = l&15;
  const long p0 = (long)blockIdx.x * 128;

  #pragma unroll
  for (int u = 0; u < 4; ++u){
    const int pr = w*4 + u;            // (rt,kt) pair 0..31
    const int rt = pr >> 2, kt = pr & 3;
    gload_lds16(obf + (p0 + rt*16 + c)*128 + kt*32 + g16*8, afr + pr*512);
  }
  asm volatile("s_waitcnt vmcnt(0)" ::: "memory");
  __syncthreads();

  bf16x8 bh[4], bl[4];
  #pragma unroll
  for (int kt = 0; kt < 4; ++kt){
    bh[kt] = *(const bf16x8*)(pko + ((w*4+kt)*2+0)*512 + l*8);
    bl[kt] = *(const bf16x8*)(pko + ((w*4+kt)*2+1)*512 + l*8);
  }
  const float bov = bo[w*16 + c];
  for (int rt = 0; rt < 8; ++rt){
    f32x4 a0 = {bov, bov, bov, bov};
    #pragma unroll
    for (int kt = 0; kt < 4; ++kt){
      bf16x8 af = *(const bf16x8*)&afr[(rt*4+kt)*512 + l*8];
      a0 = mfma16(af, bh[kt], a0);
      a0 = mfma16(af, bl[kt], a0);
    }
    const int row0 = (int)p0 + rt*16 + g16*4;
    #pragma unroll
    for (int j = 0; j < 4; ++j)
      out[(row0+j)*128 + w*16 + c] = a0[j];
  }
}

extern "C" void kernel_launch(void* const* d_in, const int* in_sizes, int n_in,
                              void* d_out, int out_size, void* d_ws, size_t ws_size,
                              hipStream_t stream) {
  const float* act  = (const float*)d_in[0];
  const float* mask = (const float*)d_in[1];
  const float* ln_g = (const float*)d_in[2];
  const float* ln_b = (const float*)d_in[3];
  const float* w2d  = (const float*)d_in[4];
  const float* wq   = (const float*)d_in[5];
  const float* wk   = (const float*)d_in[6];
  const float* wv   = (const float*)d_in[7];
  const float* wg   = (const float*)d_in[8];
  const float* bg   = (const float*)d_in[9];
  const float* wo   = (const float*)d_in[10];
  const float* bo   = (const float*)d_in[11];
  float* out = (float*)d_out;

  char* ws = (char*)d_ws;
  unsigned short* qf   = (unsigned short*)(ws);                 // 16.7 MB frag q
  unsigned short* kfb  = (unsigned short*)(ws + 16777216L);     // 16.7 MB frag k
  unsigned short* vt   = (unsigned short*)(ws + 33554432L);     // 16.7 MB swizzled V^T
  unsigned short* gg   = (unsigned short*)(ws + 50331648L);     // 16.7 MB gate bf16
  unsigned short* obf  = (unsigned short*)(ws + 67108864L);     // 16.7 MB gated o bf16
  unsigned short* b2dh = (unsigned short*)(ws + 83886080L);     // 512 KB pair bias bf16
  unsigned short* pk   = (unsigned short*)(ws + 84934656L);     // 320 KB packed weights

  k_prep<<<5, 256, 0, stream>>>(wq, wk, wv, wg, wo, pk);
  k_proj<<<512, 512, 0, stream>>>(act, ln_g, ln_b, w2d, pk, bg,
                                  qf, kfb, vt, gg, b2dh);
  k_attn<<<1024, 512, 0, stream>>>(qf, kfb, vt, gg, b2dh, mask, obf);
  k_out<<<512, 512, 0, stream>>>(obf, pk + 4*32768, bo, out);
}